// Round 1
// baseline (341.934 us; speedup 1.0000x reference)
//
#include <hip/hip_runtime.h>
#include <stdint.h>

// ---- problem constants ----
constexpr int NB   = 4;      // batch
constexpr int CIN  = 3;
constexpr int HIN  = 256;
constexpr int COUT = 256;
constexpr int HF   = 128;              // feature H=W after stride-2 conv
constexpr int NF   = HF * HF;          // 16384
constexpr int KADM = 16;
constexpr int KK   = KADM * KADM;      // 256 descriptors
constexpr int HID  = 128;              // MLP hidden

// =====================================================================
// Conv 3->256 k3 s2 p1 + ReLU, fused resp (A: sum over C) / normB (B: sum sq)
// tile: 64 wide x 4 tall outputs, block 256 threads
// =====================================================================
__global__ __launch_bounds__(256) void conv_kernel(
        const float* __restrict__ xA, const float* __restrict__ xB,
        const float* __restrict__ W,  const float* __restrict__ bias,
        float* __restrict__ fA, float* __restrict__ fB,
        float* __restrict__ resp, float* __restrict__ normB)
{
    __shared__ float pS[CIN][9][129];    // input patch (9 rows x 129 cols per ci)
    __shared__ float wS[COUT * 27];
    __shared__ float bS[COUT];

    int blk  = blockIdx.x;           // 0..511
    int img  = blk >> 6;             // 0..7 (0..3 = A, 4..7 = B)
    int tile = blk & 63;             // tileY 0..31 (4-tall), tileX 0..1 (64-wide)
    int ty0  = (tile >> 1) * 4;
    int tx0  = (tile & 1) * 64;
    int tid  = threadIdx.x;

    const float* x = (img < 4) ? (xA + (size_t)img * CIN * HIN * HIN)
                               : (xB + (size_t)(img - 4) * CIN * HIN * HIN);

    for (int i = tid; i < COUT * 27; i += 256) wS[i] = W[i];
    for (int i = tid; i < COUT; i += 256)      bS[i] = bias[i];

    // stage input patch rows [ty0*2-1 .. ty0*2+7], cols [tx0*2-1 .. tx0*2+127]
    for (int i = tid; i < CIN * 9 * 129; i += 256) {
        int ci  = i / (9 * 129);
        int rem = i % (9 * 129);
        int r = rem / 129, c = rem % 129;
        int gr = ty0 * 2 - 1 + r, gc = tx0 * 2 - 1 + c;
        float v = 0.f;
        if (gr >= 0 && gr < HIN && gc >= 0 && gc < HIN)
            v = x[(size_t)ci * HIN * HIN + (size_t)gr * HIN + gc];
        pS[ci][r][c] = v;
    }
    __syncthreads();

    int tx = tid & 63, ty = tid >> 6;
    float p[CIN][3][3];
    #pragma unroll
    for (int ci = 0; ci < CIN; ++ci)
        #pragma unroll
        for (int kh = 0; kh < 3; ++kh)
            #pragma unroll
            for (int kw = 0; kw < 3; ++kw)
                p[ci][kh][kw] = pS[ci][ty * 2 + kh][tx * 2 + kw];

    int oh = ty0 + ty, ow = tx0 + tx;
    int imgL = img & 3;
    float* f = (img < 4) ? fA : fB;
    size_t obase = (size_t)imgL * COUT * NF + (size_t)oh * HF + ow;

    float sum = 0.f, sumsq = 0.f;
    #pragma unroll 4
    for (int co = 0; co < COUT; ++co) {
        float v = bS[co];
        const float* w = &wS[co * 27];
        #pragma unroll
        for (int ci = 0; ci < CIN; ++ci)
            #pragma unroll
            for (int kh = 0; kh < 3; ++kh)
                #pragma unroll
                for (int kw = 0; kw < 3; ++kw)
                    v = fmaf(p[ci][kh][kw], w[ci * 9 + kh * 3 + kw], v);
        v = fmaxf(v, 0.f);
        f[obase + (size_t)co * NF] = v;
        sum += v;
        sumsq = fmaf(v, v, sumsq);
    }
    if (img < 4) resp [(size_t)imgL * NF + (size_t)oh * HF + ow] = sum;
    else         normB[(size_t)imgL * NF + (size_t)oh * HF + ow] = sumsq;
}

// =====================================================================
// AdaptiveMaxPool2d(16) argmax on resp; one wave per 8x8 pool block.
// Tie-break: first occurrence (smallest local flat index), like jnp.argmax.
// =====================================================================
__global__ __launch_bounds__(64) void pool_kernel(
        const float* __restrict__ resp, int* __restrict__ idxA)
{
    int bk = blockIdx.x;              // b*256 + kIdx
    int b = bk >> 8, kIdx = bk & 255;
    int kr = kIdx >> 4, kc = kIdx & 15;
    int lane = threadIdx.x;           // 0..63 == lr*8+lc (local flat index order)
    int lr = lane >> 3, lc = lane & 7;
    int row = kr * 8 + lr, col = kc * 8 + lc;

    float bv = resp[(size_t)b * NF + (size_t)row * HF + col];
    int best = lane;
    for (int off = 32; off > 0; off >>= 1) {
        float ov = __shfl_down(bv, off, 64);
        int   oi = __shfl_down(best, off, 64);
        if (ov > bv || (ov == bv && oi < best)) { bv = ov; best = oi; }
    }
    if (lane == 0) {
        int r = kr * 8 + (best >> 3), c = kc * 8 + (best & 7);
        idxA[bk] = r * HF + c;
    }
}

// =====================================================================
// Gather desc (transposed: descT[b][c][k]) + normA[b][k] = sum_c desc^2
// one block per (b,k), thread = c
// =====================================================================
__global__ __launch_bounds__(256) void gather_kernel(
        const float* __restrict__ fA, const int* __restrict__ idxA,
        float* __restrict__ descT, float* __restrict__ normA)
{
    __shared__ float red[4];
    int bk = blockIdx.x;              // b*KK + k
    int b = bk >> 8, k = bk & 255;
    int c = threadIdx.x;
    int idx = idxA[bk];
    float v = fA[((size_t)b * COUT + c) * NF + idx];
    descT[((size_t)b * COUT + c) * KK + k] = v;
    float s = v * v;
    for (int off = 32; off > 0; off >>= 1) s += __shfl_down(s, off, 64);
    if ((c & 63) == 0) red[c >> 6] = s;
    __syncthreads();
    if (c == 0) normA[bk] = red[0] + red[1] + red[2] + red[3];
}

// =====================================================================
// Fused dist + argmin:  dist[b,k,n] = (normA[k] - 2*dot(desc_k, fB_n)) + normB[n]
// grid (nb=64, kb=4, b=4), block 256 (thread = one n), 64 k's per block in LDS.
// Result packed (sortable-dist<<32 | n) -> atomicMin => min dist, tie -> min n.
// =====================================================================
__device__ inline unsigned long long shfl_down_u64(unsigned long long v, int off) {
    unsigned lo = (unsigned)v, hi = (unsigned)(v >> 32);
    lo = __shfl_down(lo, off, 64);
    hi = __shfl_down(hi, off, 64);
    return ((unsigned long long)hi << 32) | lo;
}

__global__ __launch_bounds__(256) void knn_kernel(
        const float* __restrict__ fB, const float* __restrict__ descT,
        const float* __restrict__ normA, const float* __restrict__ normB,
        unsigned long long* __restrict__ packed)
{
    __shared__ float descS[COUT * 64];          // [c][k] 64 KB
    __shared__ float nAS[64];
    __shared__ unsigned long long part[4][64];

    int nb = blockIdx.x;     // 0..63
    int kb = blockIdx.y;     // 0..3
    int b  = blockIdx.z;     // 0..3
    int tid = threadIdx.x;

    const float* dsrc = descT + (size_t)b * COUT * KK + kb * 64;
    for (int i = tid; i < COUT * 64; i += 256) {
        int c = i >> 6, k = i & 63;
        descS[i] = dsrc[(size_t)c * KK + k];
    }
    if (tid < 64) nAS[tid] = normA[b * KK + kb * 64 + tid];
    __syncthreads();

    int n = nb * 256 + tid;
    float nv = normB[(size_t)b * NF + n];

    float acc[64];
    #pragma unroll
    for (int k = 0; k < 64; ++k) acc[k] = 0.f;

    const float* fp = fB + (size_t)b * COUT * NF + n;
    #pragma unroll 1
    for (int c = 0; c < COUT; ++c) {
        float bv = fp[(size_t)c * NF];
        const float* ds = &descS[c * 64];
        #pragma unroll
        for (int k = 0; k < 64; ++k) acc[k] = fmaf(bv, ds[k], acc[k]);
    }

    #pragma unroll 1
    for (int k = 0; k < 64; ++k) {
        float d = (nAS[k] - 2.0f * acc[k]) + nv;
        unsigned u = __float_as_uint(d);
        u = (u & 0x80000000u) ? ~u : (u | 0x80000000u);
        unsigned long long key = ((unsigned long long)u << 32) | (unsigned)n;
        for (int off = 32; off > 0; off >>= 1) {
            unsigned long long o = shfl_down_u64(key, off);
            key = (o < key) ? o : key;
        }
        if ((tid & 63) == 0) part[tid >> 6][k] = key;
    }
    __syncthreads();
    if (tid < 64) {
        unsigned long long k0 = part[0][tid], k1 = part[1][tid];
        unsigned long long k2 = part[2][tid], k3 = part[3][tid];
        unsigned long long a = (k1 < k0) ? k1 : k0;
        unsigned long long c2 = (k3 < k2) ? k3 : k2;
        unsigned long long key = (c2 < a) ? c2 : a;
        atomicMin(&packed[b * KK + kb * 64 + tid], key);
    }
}

// =====================================================================
// Two tiny MLPs: x(256) -> 128 relu -> 1. block per (b, which), 128 threads.
// =====================================================================
__global__ __launch_bounds__(128) void mlp_kernel(
        const int* __restrict__ idxA, const unsigned long long* __restrict__ packed,
        const float* __restrict__ W1r, const float* __restrict__ b1r,
        const float* __restrict__ W2r, const float* __restrict__ b2r,
        const float* __restrict__ W1c, const float* __restrict__ b1c,
        const float* __restrict__ W2c, const float* __restrict__ b2c,
        float* __restrict__ out)
{
    __shared__ float xS[KK];
    __shared__ float red[2];
    int blk = blockIdx.x;            // b*2 + which
    int b = blk >> 1, which = blk & 1;
    int t = threadIdx.x;             // 0..127

    for (int k = t; k < KK; k += 128) {
        int ia = idxA[b * KK + k];
        unsigned nn = (unsigned)(packed[b * KK + k] & 0xffffffffULL);
        int rowA = ia >> 7, colA = ia & 127;     // // H and % H, H=128
        int rowB = (int)(nn >> 7), colB = (int)(nn & 127u);
        xS[k] = (which == 0) ? (float)(rowB - rowA) : (float)(colA - colB);
    }
    __syncthreads();

    const float* W1 = which ? W1c : W1r;
    const float* b1 = which ? b1c : b1r;
    const float* W2 = which ? W2c : W2r;
    const float* b2 = which ? b2c : b2r;

    float h = b1[t];
    for (int k = 0; k < KK; ++k) h = fmaf(xS[k], W1[k * HID + t], h);
    h = fmaxf(h, 0.f);
    float pv = h * W2[t];
    for (int off = 32; off > 0; off >>= 1) pv += __shfl_down(pv, off, 64);
    if ((t & 63) == 0) red[t >> 6] = pv;
    __syncthreads();
    if (t == 0) out[b * 2 + which] = red[0] + red[1] + b2[0];
}

// =====================================================================
extern "C" void kernel_launch(void* const* d_in, const int* in_sizes, int n_in,
                              void* d_out, int out_size, void* d_ws, size_t ws_size,
                              hipStream_t stream)
{
    const float* xA  = (const float*)d_in[0];
    const float* xB  = (const float*)d_in[1];
    const float* Wc  = (const float*)d_in[2];
    const float* bc  = (const float*)d_in[3];
    const float* W1r = (const float*)d_in[4];
    const float* b1r = (const float*)d_in[5];
    const float* W2r = (const float*)d_in[6];
    const float* b2r = (const float*)d_in[7];
    const float* W1c = (const float*)d_in[8];
    const float* b1c = (const float*)d_in[9];
    const float* W2c = (const float*)d_in[10];
    const float* b2c = (const float*)d_in[11];
    float* out = (float*)d_out;

    char* ws = (char*)d_ws;
    unsigned long long* packed = (unsigned long long*)ws; ws += (size_t)NB * KK * 8;
    int*   idxA  = (int*)ws;   ws += (size_t)NB * KK * 4;
    float* normA = (float*)ws; ws += (size_t)NB * KK * 4;
    float* resp  = (float*)ws; ws += (size_t)NB * NF * 4;
    float* normB = (float*)ws; ws += (size_t)NB * NF * 4;
    float* descT = (float*)ws; ws += (size_t)NB * COUT * KK * 4;
    float* fA    = (float*)ws; ws += (size_t)NB * COUT * NF * 4;
    float* fB    = (float*)ws; ws += (size_t)NB * COUT * NF * 4;

    hipMemsetAsync(packed, 0xFF, (size_t)NB * KK * 8, stream);  // +inf keys

    conv_kernel  <<<512, 256, 0, stream>>>(xA, xB, Wc, bc, fA, fB, resp, normB);
    pool_kernel  <<<NB * KK, 64, 0, stream>>>(resp, idxA);
    gather_kernel<<<NB * KK, 256, 0, stream>>>(fA, idxA, descT, normA);
    knn_kernel   <<<dim3(64, 4, 4), 256, 0, stream>>>(fB, descT, normA, normB, packed);
    mlp_kernel   <<<8, 128, 0, stream>>>(idxA, packed,
                                         W1r, b1r, W2r, b2r,
                                         W1c, b1c, W2c, b2c, out);
}

// Round 2
// 188.550 us; speedup vs baseline: 1.8135x; 1.8135x over previous
//
#include <hip/hip_runtime.h>
#include <stdint.h>

// ---- problem constants ----
constexpr int NB   = 4;      // batch
constexpr int CIN  = 3;
constexpr int HIN  = 256;
constexpr int COUT = 256;
constexpr int HF   = 128;              // feature H=W after stride-2 conv
constexpr int NF   = HF * HF;          // 16384
constexpr int KADM = 16;
constexpr int KK   = KADM * KADM;      // 256 descriptors
constexpr int HID  = 128;              // MLP hidden

// =====================================================================
// Conv 3->256 k3 s2 p1 + ReLU, fused resp (A: sum over C) / normB (B: sum sq)
// tile: 64 wide x 4 tall outputs, block 256 threads
// =====================================================================
__global__ __launch_bounds__(256) void conv_kernel(
        const float* __restrict__ xA, const float* __restrict__ xB,
        const float* __restrict__ W,  const float* __restrict__ bias,
        float* __restrict__ fA, float* __restrict__ fB,
        float* __restrict__ resp, float* __restrict__ normB)
{
    __shared__ float pS[CIN][9][129];    // input patch (9 rows x 129 cols per ci)
    __shared__ float wS[COUT * 27];
    __shared__ float bS[COUT];

    int blk  = blockIdx.x;           // 0..511
    int img  = blk >> 6;             // 0..7 (0..3 = A, 4..7 = B)
    int tile = blk & 63;             // tileY 0..31 (4-tall), tileX 0..1 (64-wide)
    int ty0  = (tile >> 1) * 4;
    int tx0  = (tile & 1) * 64;
    int tid  = threadIdx.x;

    const float* x = (img < 4) ? (xA + (size_t)img * CIN * HIN * HIN)
                               : (xB + (size_t)(img - 4) * CIN * HIN * HIN);

    for (int i = tid; i < COUT * 27; i += 256) wS[i] = W[i];
    for (int i = tid; i < COUT; i += 256)      bS[i] = bias[i];

    // stage input patch rows [ty0*2-1 .. ty0*2+7], cols [tx0*2-1 .. tx0*2+127]
    for (int i = tid; i < CIN * 9 * 129; i += 256) {
        int ci  = i / (9 * 129);
        int rem = i % (9 * 129);
        int r = rem / 129, c = rem % 129;
        int gr = ty0 * 2 - 1 + r, gc = tx0 * 2 - 1 + c;
        float v = 0.f;
        if (gr >= 0 && gr < HIN && gc >= 0 && gc < HIN)
            v = x[(size_t)ci * HIN * HIN + (size_t)gr * HIN + gc];
        pS[ci][r][c] = v;
    }
    __syncthreads();

    int tx = tid & 63, ty = tid >> 6;
    float p[CIN][3][3];
    #pragma unroll
    for (int ci = 0; ci < CIN; ++ci)
        #pragma unroll
        for (int kh = 0; kh < 3; ++kh)
            #pragma unroll
            for (int kw = 0; kw < 3; ++kw)
                p[ci][kh][kw] = pS[ci][ty * 2 + kh][tx * 2 + kw];

    int oh = ty0 + ty, ow = tx0 + tx;
    int imgL = img & 3;
    float* f = (img < 4) ? fA : fB;
    size_t obase = (size_t)imgL * COUT * NF + (size_t)oh * HF + ow;

    float sum = 0.f, sumsq = 0.f;
    #pragma unroll 4
    for (int co = 0; co < COUT; ++co) {
        float v = bS[co];
        const float* w = &wS[co * 27];
        #pragma unroll
        for (int ci = 0; ci < CIN; ++ci)
            #pragma unroll
            for (int kh = 0; kh < 3; ++kh)
                #pragma unroll
                for (int kw = 0; kw < 3; ++kw)
                    v = fmaf(p[ci][kh][kw], w[ci * 9 + kh * 3 + kw], v);
        v = fmaxf(v, 0.f);
        f[obase + (size_t)co * NF] = v;
        sum += v;
        sumsq = fmaf(v, v, sumsq);
    }
    if (img < 4) resp [(size_t)imgL * NF + (size_t)oh * HF + ow] = sum;
    else         normB[(size_t)imgL * NF + (size_t)oh * HF + ow] = sumsq;
}

// =====================================================================
// AdaptiveMaxPool2d(16) argmax on resp; one wave per 8x8 pool block.
// =====================================================================
__global__ __launch_bounds__(64) void pool_kernel(
        const float* __restrict__ resp, int* __restrict__ idxA)
{
    int bk = blockIdx.x;              // b*256 + kIdx
    int b = bk >> 8, kIdx = bk & 255;
    int kr = kIdx >> 4, kc = kIdx & 15;
    int lane = threadIdx.x;           // 0..63 == lr*8+lc (local flat index order)
    int lr = lane >> 3, lc = lane & 7;
    int row = kr * 8 + lr, col = kc * 8 + lc;

    float bv = resp[(size_t)b * NF + (size_t)row * HF + col];
    int best = lane;
    for (int off = 32; off > 0; off >>= 1) {
        float ov = __shfl_down(bv, off, 64);
        int   oi = __shfl_down(best, off, 64);
        if (ov > bv || (ov == bv && oi < best)) { bv = ov; best = oi; }
    }
    if (lane == 0) {
        int r = kr * 8 + (best >> 3), c = kc * 8 + (best & 7);
        idxA[bk] = r * HF + c;
    }
}

// =====================================================================
// Gather desc (transposed: descT[b][c][k]) + normA[b][k] = sum_c desc^2
// =====================================================================
__global__ __launch_bounds__(256) void gather_kernel(
        const float* __restrict__ fA, const int* __restrict__ idxA,
        float* __restrict__ descT, float* __restrict__ normA)
{
    __shared__ float red[4];
    int bk = blockIdx.x;              // b*KK + k
    int b = bk >> 8, k = bk & 255;
    int c = threadIdx.x;
    int idx = idxA[bk];
    float v = fA[((size_t)b * COUT + c) * NF + idx];
    descT[((size_t)b * COUT + c) * KK + k] = v;
    float s = v * v;
    for (int off = 32; off > 0; off >>= 1) s += __shfl_down(s, off, 64);
    if ((c & 63) == 0) red[c >> 6] = s;
    __syncthreads();
    if (c == 0) normA[bk] = red[0] + red[1] + red[2] + red[3];
}

// =====================================================================
// Fused dist + argmin, register-tiled 8k x 8n per thread.
// Block: 256 thr = 8 kt-groups x 32 nt. Tile: 64 k x 256 n, C chunked by 32.
// Thread (kt,nt): k = kt*8+i ; n = nb*256 + (j<4 ? nt*4+j : 128+nt*4+j-4)
// LDS: descS[32][64] (8KB) + fBS[32][256] (32KB) -> 4 blocks/CU.
// =====================================================================
__global__ __launch_bounds__(256) void knn_kernel(
        const float* __restrict__ fB, const float* __restrict__ descT,
        const float* __restrict__ normA, const float* __restrict__ normB,
        unsigned long long* __restrict__ packed)
{
    __shared__ float descS[32][64];
    __shared__ float fBS[32][256];
    __shared__ float nAS[64];

    int nb = blockIdx.x;     // 0..63
    int kb = blockIdx.y;     // 0..3
    int b  = blockIdx.z;     // 0..3
    int tid = threadIdx.x;
    int kt = tid >> 5, nt = tid & 31;

    if (tid < 64) nAS[tid] = normA[b * KK + kb * 64 + tid];

    const float* dbase = descT + (size_t)b * COUT * KK + kb * 64;
    const float* fbase = fB    + (size_t)b * COUT * NF + nb * 256;

    float acc[8][8];
    #pragma unroll
    for (int i = 0; i < 8; ++i)
        #pragma unroll
        for (int j = 0; j < 8; ++j) acc[i][j] = 0.f;

    for (int cc = 0; cc < COUT; cc += 32) {
        __syncthreads();
        // stage descS: 32 rows x 16 float4
        for (int i = tid; i < 32 * 16; i += 256) {
            int r = i >> 4, q = i & 15;
            *(float4*)&descS[r][q * 4] =
                *(const float4*)&dbase[(size_t)(cc + r) * KK + q * 4];
        }
        // stage fBS: 32 rows x 64 float4
        for (int i = tid; i < 32 * 64; i += 256) {
            int r = i >> 6, q = i & 63;
            *(float4*)&fBS[r][q * 4] =
                *(const float4*)&fbase[(size_t)(cc + r) * NF + q * 4];
        }
        __syncthreads();

        #pragma unroll 4
        for (int c = 0; c < 32; ++c) {
            const float4 a0 = *(const float4*)&descS[c][kt * 8];
            const float4 a1 = *(const float4*)&descS[c][kt * 8 + 4];
            const float4 f0 = *(const float4*)&fBS[c][nt * 4];
            const float4 f1 = *(const float4*)&fBS[c][128 + nt * 4];
            float ka[8]  = {a0.x, a0.y, a0.z, a0.w, a1.x, a1.y, a1.z, a1.w};
            float fb8[8] = {f0.x, f0.y, f0.z, f0.w, f1.x, f1.y, f1.z, f1.w};
            #pragma unroll
            for (int i = 0; i < 8; ++i)
                #pragma unroll
                for (int j = 0; j < 8; ++j)
                    acc[i][j] = fmaf(ka[i], fb8[j], acc[i][j]);
        }
    }

    // epilogue: fold norms, pack (dist,n), reduce over n
    int n0 = nb * 256;
    const float4 v0 = *(const float4*)&normB[(size_t)b * NF + n0 + nt * 4];
    const float4 v1 = *(const float4*)&normB[(size_t)b * NF + n0 + 128 + nt * 4];
    float nv[8] = {v0.x, v0.y, v0.z, v0.w, v1.x, v1.y, v1.z, v1.w};

    unsigned long long bestk[8];
    #pragma unroll
    for (int i = 0; i < 8; ++i) {
        float nA = nAS[kt * 8 + i];
        unsigned long long best = ~0ull;
        #pragma unroll
        for (int j = 0; j < 8; ++j) {
            int n = n0 + (j < 4 ? nt * 4 + j : 128 + nt * 4 + (j - 4));
            float d = (nA - 2.0f * acc[i][j]) + nv[j];
            unsigned u = __float_as_uint(d);
            u = (u & 0x80000000u) ? ~u : (u | 0x80000000u);
            unsigned long long key = ((unsigned long long)u << 32) | (unsigned)n;
            best = (key < best) ? key : best;
        }
        // reduce across the 32 nt lanes of this kt group
        for (int off = 16; off > 0; off >>= 1) {
            unsigned long long o = __shfl_down(best, off, 32);
            best = (o < best) ? o : best;
        }
        bestk[i] = best;
    }
    if (nt == 0) {
        #pragma unroll
        for (int i = 0; i < 8; ++i)
            atomicMin(&packed[b * KK + kb * 64 + kt * 8 + i], bestk[i]);
    }
}

// =====================================================================
// Two tiny MLPs: x(256) -> 128 relu -> 1. block per (b, which), 128 threads.
// =====================================================================
__global__ __launch_bounds__(128) void mlp_kernel(
        const int* __restrict__ idxA, const unsigned long long* __restrict__ packed,
        const float* __restrict__ W1r, const float* __restrict__ b1r,
        const float* __restrict__ W2r, const float* __restrict__ b2r,
        const float* __restrict__ W1c, const float* __restrict__ b1c,
        const float* __restrict__ W2c, const float* __restrict__ b2c,
        float* __restrict__ out)
{
    __shared__ float xS[KK];
    __shared__ float red[2];
    int blk = blockIdx.x;            // b*2 + which
    int b = blk >> 1, which = blk & 1;
    int t = threadIdx.x;             // 0..127

    for (int k = t; k < KK; k += 128) {
        int ia = idxA[b * KK + k];
        unsigned nn = (unsigned)(packed[b * KK + k] & 0xffffffffULL);
        int rowA = ia >> 7, colA = ia & 127;     // // H and % H, H=128
        int rowB = (int)(nn >> 7), colB = (int)(nn & 127u);
        xS[k] = (which == 0) ? (float)(rowB - rowA) : (float)(colA - colB);
    }
    __syncthreads();

    const float* W1 = which ? W1c : W1r;
    const float* b1 = which ? b1c : b1r;
    const float* W2 = which ? W2c : W2r;
    const float* b2 = which ? b2c : b2r;

    float h = b1[t];
    for (int k = 0; k < KK; ++k) h = fmaf(xS[k], W1[k * HID + t], h);
    h = fmaxf(h, 0.f);
    float pv = h * W2[t];
    for (int off = 32; off > 0; off >>= 1) pv += __shfl_down(pv, off, 64);
    if ((t & 63) == 0) red[t >> 6] = pv;
    __syncthreads();
    if (t == 0) out[b * 2 + which] = red[0] + red[1] + b2[0];
}

// =====================================================================
extern "C" void kernel_launch(void* const* d_in, const int* in_sizes, int n_in,
                              void* d_out, int out_size, void* d_ws, size_t ws_size,
                              hipStream_t stream)
{
    const float* xA  = (const float*)d_in[0];
    const float* xB  = (const float*)d_in[1];
    const float* Wc  = (const float*)d_in[2];
    const float* bc  = (const float*)d_in[3];
    const float* W1r = (const float*)d_in[4];
    const float* b1r = (const float*)d_in[5];
    const float* W2r = (const float*)d_in[6];
    const float* b2r = (const float*)d_in[7];
    const float* W1c = (const float*)d_in[8];
    const float* b1c = (const float*)d_in[9];
    const float* W2c = (const float*)d_in[10];
    const float* b2c = (const float*)d_in[11];
    float* out = (float*)d_out;

    char* ws = (char*)d_ws;
    unsigned long long* packed = (unsigned long long*)ws; ws += (size_t)NB * KK * 8;
    int*   idxA  = (int*)ws;   ws += (size_t)NB * KK * 4;
    float* normA = (float*)ws; ws += (size_t)NB * KK * 4;
    float* resp  = (float*)ws; ws += (size_t)NB * NF * 4;
    float* normB = (float*)ws; ws += (size_t)NB * NF * 4;
    float* descT = (float*)ws; ws += (size_t)NB * COUT * KK * 4;
    float* fA    = (float*)ws; ws += (size_t)NB * COUT * NF * 4;
    float* fB    = (float*)ws; ws += (size_t)NB * COUT * NF * 4;

    hipMemsetAsync(packed, 0xFF, (size_t)NB * KK * 8, stream);  // +inf keys

    conv_kernel  <<<512, 256, 0, stream>>>(xA, xB, Wc, bc, fA, fB, resp, normB);
    pool_kernel  <<<NB * KK, 64, 0, stream>>>(resp, idxA);
    gather_kernel<<<NB * KK, 256, 0, stream>>>(fA, idxA, descT, normA);
    knn_kernel   <<<dim3(64, 4, 4), 256, 0, stream>>>(fB, descT, normA, normB, packed);
    mlp_kernel   <<<8, 128, 0, stream>>>(idxA, packed,
                                         W1r, b1r, W2r, b2r,
                                         W1c, b1c, W2c, b2c, out);
}

// Round 3
// 135.296 us; speedup vs baseline: 2.5273x; 1.3936x over previous
//
#include <hip/hip_runtime.h>
#include <stdint.h>

// ---- problem constants ----
constexpr int NB   = 4;      // batch
constexpr int CIN  = 3;
constexpr int HIN  = 256;
constexpr int COUT = 256;
constexpr int HF   = 128;              // feature H=W after stride-2 conv
constexpr int NF   = HF * HF;          // 16384
constexpr int KADM = 16;
constexpr int KK   = KADM * KADM;      // 256 descriptors
constexpr int HID  = 128;              // MLP hidden

typedef unsigned short ushort_t;
typedef __attribute__((ext_vector_type(8))) _Float16 f16x8;
typedef __attribute__((ext_vector_type(4))) float    f32x4;

__device__ inline unsigned long long shfl_xor_u64(unsigned long long v, int m) {
    unsigned lo = __shfl_xor((unsigned)v, m, 64);
    unsigned hi = __shfl_xor((unsigned)(v >> 32), m, 64);
    return ((unsigned long long)hi << 32) | lo;
}
__device__ inline unsigned long long shfl_down_u64(unsigned long long v, int off) {
    unsigned lo = __shfl_down((unsigned)v, off, 64);
    unsigned hi = __shfl_down((unsigned)(v >> 32), off, 64);
    return ((unsigned long long)hi << 32) | lo;
}
__device__ inline unsigned long long u64min(unsigned long long a, unsigned long long b) {
    return a < b ? a : b;
}

// =====================================================================
// Conv 3->256 k3 s2 p1 + ReLU.
// A-images: emit only resp = sum_c (for pooling). No fA store.
// B-images: emit fB fp32 [c][n] + normB = sum_c v^2.
// =====================================================================
__global__ __launch_bounds__(256) void conv_kernel(
        const float* __restrict__ xA, const float* __restrict__ xB,
        const float* __restrict__ W,  const float* __restrict__ bias,
        float* __restrict__ fB, float* __restrict__ resp, float* __restrict__ normB)
{
    __shared__ float pS[CIN][9][129];
    __shared__ float wS[COUT * 27];
    __shared__ float bS[COUT];

    int blk  = blockIdx.x;           // 0..511
    int img  = blk >> 6;             // 0..7 (0..3 = A, 4..7 = B)
    int tile = blk & 63;
    int ty0  = (tile >> 1) * 4;
    int tx0  = (tile & 1) * 64;
    int tid  = threadIdx.x;
    bool isA = (img < 4);

    const float* x = isA ? (xA + (size_t)img * CIN * HIN * HIN)
                         : (xB + (size_t)(img - 4) * CIN * HIN * HIN);

    for (int i = tid; i < COUT * 27; i += 256) wS[i] = W[i];
    for (int i = tid; i < COUT; i += 256)      bS[i] = bias[i];

    for (int i = tid; i < CIN * 9 * 129; i += 256) {
        int ci  = i / (9 * 129);
        int rem = i % (9 * 129);
        int r = rem / 129, c = rem % 129;
        int gr = ty0 * 2 - 1 + r, gc = tx0 * 2 - 1 + c;
        float v = 0.f;
        if (gr >= 0 && gr < HIN && gc >= 0 && gc < HIN)
            v = x[(size_t)ci * HIN * HIN + (size_t)gr * HIN + gc];
        pS[ci][r][c] = v;
    }
    __syncthreads();

    int tx = tid & 63, ty = tid >> 6;
    float p[CIN][3][3];
    #pragma unroll
    for (int ci = 0; ci < CIN; ++ci)
        #pragma unroll
        for (int kh = 0; kh < 3; ++kh)
            #pragma unroll
            for (int kw = 0; kw < 3; ++kw)
                p[ci][kh][kw] = pS[ci][ty * 2 + kh][tx * 2 + kw];

    int oh = ty0 + ty, ow = tx0 + tx;
    int imgL = img & 3;
    size_t obase = (size_t)imgL * COUT * NF + (size_t)oh * HF + ow;

    float sum = 0.f, sumsq = 0.f;
    #pragma unroll 4
    for (int co = 0; co < COUT; ++co) {
        float v = bS[co];
        const float* w = &wS[co * 27];
        #pragma unroll
        for (int ci = 0; ci < CIN; ++ci)
            #pragma unroll
            for (int kh = 0; kh < 3; ++kh)
                #pragma unroll
                for (int kw = 0; kw < 3; ++kw)
                    v = fmaf(p[ci][kh][kw], w[ci * 9 + kh * 3 + kw], v);
        v = fmaxf(v, 0.f);
        if (!isA) fB[obase + (size_t)co * NF] = v;
        sum += v;
        sumsq = fmaf(v, v, sumsq);
    }
    if (isA) resp [(size_t)imgL * NF + (size_t)oh * HF + ow] = sum;
    else     normB[(size_t)imgL * NF + (size_t)oh * HF + ow] = sumsq;
}

// =====================================================================
// AdaptiveMaxPool2d(16) argmax on resp; one wave per 8x8 pool block.
// =====================================================================
__global__ __launch_bounds__(64) void pool_kernel(
        const float* __restrict__ resp, int* __restrict__ idxA)
{
    int bk = blockIdx.x;
    int b = bk >> 8, kIdx = bk & 255;
    int kr = kIdx >> 4, kc = kIdx & 15;
    int lane = threadIdx.x;
    int lr = lane >> 3, lc = lane & 7;
    int row = kr * 8 + lr, col = kc * 8 + lc;

    float bv = resp[(size_t)b * NF + (size_t)row * HF + col];
    int best = lane;
    for (int off = 32; off > 0; off >>= 1) {
        float ov = __shfl_down(bv, off, 64);
        int   oi = __shfl_down(best, off, 64);
        if (ov > bv || (ov == bv && oi < best)) { bv = ov; best = oi; }
    }
    if (lane == 0) {
        int r = kr * 8 + (best >> 3), c = kc * 8 + (best & 7);
        idxA[bk] = r * HF + c;
    }
}

// =====================================================================
// Gather: recompute conv at selected pixel (27 FMA per channel), emit
// desc f16 hi/lo pairs [b*KK + k][c] + normA (fp32).
// =====================================================================
__global__ __launch_bounds__(256) void gather_kernel(
        const float* __restrict__ xA, const float* __restrict__ W,
        const float* __restrict__ bias, const int* __restrict__ idxA,
        ushort_t* __restrict__ desc_h, ushort_t* __restrict__ desc_l,
        float* __restrict__ normA)
{
    __shared__ float patch[27];
    __shared__ float red[4];
    int bk = blockIdx.x;              // b*KK + k
    int b = bk >> 8;
    int t = threadIdx.x;              // channel
    int idx = idxA[bk];
    int oh = idx >> 7, ow = idx & 127;

    if (t < 27) {
        int ci = t / 9, kh = (t % 9) / 3, kw = t % 3;
        int ir = oh * 2 - 1 + kh, ic = ow * 2 - 1 + kw;
        float v = 0.f;
        if (ir >= 0 && ir < HIN && ic >= 0 && ic < HIN)
            v = xA[((size_t)b * CIN + ci) * HIN * HIN + (size_t)ir * HIN + ic];
        patch[t] = v;
    }
    __syncthreads();

    float v = bias[t];
    const float* w = &W[t * 27];
    #pragma unroll
    for (int q = 0; q < 27; ++q) v = fmaf(patch[q], w[q], v);
    v = fmaxf(v, 0.f);

    _Float16 h = (_Float16)v;
    _Float16 l = (_Float16)(v - (float)h);
    desc_h[(size_t)bk * COUT + t] = __builtin_bit_cast(ushort_t, h);
    desc_l[(size_t)bk * COUT + t] = __builtin_bit_cast(ushort_t, l);

    float s = v * v;
    for (int off = 32; off > 0; off >>= 1) s += __shfl_down(s, off, 64);
    if ((t & 63) == 0) red[t >> 6] = s;
    __syncthreads();
    if (t == 0) normA[bk] = red[0] + red[1] + red[2] + red[3];
}

// =====================================================================
// MFMA kNN: per block (nb,b): 64 pixels x 256 k, K=c chunked by 32.
// fp16x2 split: dot = fh*dh + fl*dh + fh*dl (3 passes, no-cancellation data).
// A-operand (M=pixel) from LDS fp16 tiles (converted from fp32 fB on the fly);
// B-operand (N=k) f16 pairs direct from global (L2-hot, tiny).
// D frag: pixel=(lane>>4)*4+reg (+i*16), k=lane&15 (+j*16) [guide-verified].
// Epilogue: per-k key=(sortable(dist)<<32|n), 2 xor-shfls, store to scratch.
// =====================================================================
__global__ __launch_bounds__(256) void knn_kernel(
        const float* __restrict__ fB,
        const ushort_t* __restrict__ desc_h, const ushort_t* __restrict__ desc_l,
        const float* __restrict__ normA, const float* __restrict__ normB,
        unsigned long long* __restrict__ scratch)
{
    __shared__ ushort_t Bs[2][64][40];   // [hi/lo][n][c-chunk], 80B row stride
    __shared__ float nAS[KK];
    __shared__ float nBS[64];

    int nb = blockIdx.x;      // 0..255
    int b  = blockIdx.y;      // 0..3
    int tid = threadIdx.x;
    int lane = tid & 63, w = tid >> 6;
    int n0 = nb * 64;

    if (tid < 64) nBS[tid] = normB[(size_t)b * NF + n0 + tid];
    nAS[tid] = normA[b * KK + tid];

    const float* fBp = fB + (size_t)b * COUT * NF;
    const ushort_t* dh = desc_h + (size_t)b * KK * COUT;
    const ushort_t* dl = desc_l + (size_t)b * KK * COUT;

    f32x4 acc[4][4];
    #pragma unroll
    for (int i = 0; i < 4; ++i)
        #pragma unroll
        for (int j = 0; j < 4; ++j) acc[i][j] = (f32x4)0.f;

    int sn  = tid >> 2;       // staging pixel row 0..63
    int cp0 = tid & 3;        // staging c-pair base

    int la = lane & 15, lg = lane >> 4;   // fragment indices
    int kw0 = w * 64;

    for (int cc = 0; cc < COUT; cc += 32) {
        __syncthreads();
        #pragma unroll
        for (int it = 0; it < 4; ++it) {
            int c = (cp0 + it * 4) * 2;
            float v0 = fBp[(size_t)(cc + c)     * NF + n0 + sn];
            float v1 = fBp[(size_t)(cc + c + 1) * NF + n0 + sn];
            _Float16 h0 = (_Float16)v0, h1 = (_Float16)v1;
            _Float16 l0 = (_Float16)(v0 - (float)h0), l1 = (_Float16)(v1 - (float)h1);
            unsigned uh = (unsigned)__builtin_bit_cast(ushort_t, h0)
                        | ((unsigned)__builtin_bit_cast(ushort_t, h1) << 16);
            unsigned ul = (unsigned)__builtin_bit_cast(ushort_t, l0)
                        | ((unsigned)__builtin_bit_cast(ushort_t, l1) << 16);
            *(unsigned*)&Bs[0][sn][c] = uh;
            *(unsigned*)&Bs[1][sn][c] = ul;
        }
        __syncthreads();

        f16x8 bfrag[4], afrag[4];
        // pass 1: fh * dh
        #pragma unroll
        for (int j = 0; j < 4; ++j)
            bfrag[j] = *(const f16x8*)&dh[(size_t)(kw0 + j * 16 + la) * COUT + cc + lg * 8];
        #pragma unroll
        for (int i = 0; i < 4; ++i)
            afrag[i] = *(const f16x8*)&Bs[0][i * 16 + la][lg * 8];
        #pragma unroll
        for (int i = 0; i < 4; ++i)
            #pragma unroll
            for (int j = 0; j < 4; ++j)
                acc[i][j] = __builtin_amdgcn_mfma_f32_16x16x32_f16(afrag[i], bfrag[j], acc[i][j], 0, 0, 0);
        // pass 2: fl * dh
        #pragma unroll
        for (int i = 0; i < 4; ++i)
            afrag[i] = *(const f16x8*)&Bs[1][i * 16 + la][lg * 8];
        #pragma unroll
        for (int i = 0; i < 4; ++i)
            #pragma unroll
            for (int j = 0; j < 4; ++j)
                acc[i][j] = __builtin_amdgcn_mfma_f32_16x16x32_f16(afrag[i], bfrag[j], acc[i][j], 0, 0, 0);
        // pass 3: fh * dl
        #pragma unroll
        for (int j = 0; j < 4; ++j)
            bfrag[j] = *(const f16x8*)&dl[(size_t)(kw0 + j * 16 + la) * COUT + cc + lg * 8];
        #pragma unroll
        for (int i = 0; i < 4; ++i)
            afrag[i] = *(const f16x8*)&Bs[0][i * 16 + la][lg * 8];
        #pragma unroll
        for (int i = 0; i < 4; ++i)
            #pragma unroll
            for (int j = 0; j < 4; ++j)
                acc[i][j] = __builtin_amdgcn_mfma_f32_16x16x32_f16(afrag[i], bfrag[j], acc[i][j], 0, 0, 0);
    }

    // ---- epilogue: dist + per-k argmin ----
    float nBv[4][4];
    #pragma unroll
    for (int i = 0; i < 4; ++i) {
        f32x4 t4 = *(const f32x4*)&nBS[i * 16 + lg * 4];
        nBv[i][0] = t4[0]; nBv[i][1] = t4[1]; nBv[i][2] = t4[2]; nBv[i][3] = t4[3];
    }
    #pragma unroll
    for (int j = 0; j < 4; ++j) {
        int kl = kw0 + j * 16 + la;
        float nAv = nAS[kl];
        unsigned long long best = ~0ull;
        #pragma unroll
        for (int i = 0; i < 4; ++i)
            #pragma unroll
            for (int r = 0; r < 4; ++r) {
                int n = n0 + i * 16 + lg * 4 + r;
                float d = fmaf(-2.f, acc[i][j][r], nAv) + nBv[i][r];
                unsigned u = __float_as_uint(d);
                u = (u & 0x80000000u) ? ~u : (u | 0x80000000u);
                unsigned long long key = ((unsigned long long)u << 32) | (unsigned)n;
                best = u64min(best, key);
            }
        best = u64min(best, shfl_xor_u64(best, 16));
        best = u64min(best, shfl_xor_u64(best, 32));
        if (lg == 0)
            scratch[(size_t)(b * KK + kl) * 256 + nb] = best;
    }
}

// =====================================================================
// Final argmin reduce over the 256 nb-blocks -> minN[b*KK + k]
// =====================================================================
__global__ __launch_bounds__(64) void reduce_kernel(
        const unsigned long long* __restrict__ scratch, int* __restrict__ minN)
{
    int bk = blockIdx.x;              // b*KK + k
    int t = threadIdx.x;
    const unsigned long long* s = scratch + (size_t)bk * 256;
    unsigned long long best = s[t];
    best = u64min(best, s[t + 64]);
    best = u64min(best, s[t + 128]);
    best = u64min(best, s[t + 192]);
    for (int off = 32; off > 0; off >>= 1)
        best = u64min(best, shfl_down_u64(best, off));
    if (t == 0) minN[bk] = (int)(best & 0xffffffffULL);
}

// =====================================================================
// Two tiny MLPs: x(256) -> 128 relu -> 1. block per (b, which), 128 threads.
// =====================================================================
__global__ __launch_bounds__(128) void mlp_kernel(
        const int* __restrict__ idxA, const int* __restrict__ minN,
        const float* __restrict__ W1r, const float* __restrict__ b1r,
        const float* __restrict__ W2r, const float* __restrict__ b2r,
        const float* __restrict__ W1c, const float* __restrict__ b1c,
        const float* __restrict__ W2c, const float* __restrict__ b2c,
        float* __restrict__ out)
{
    __shared__ float xS[KK];
    __shared__ float red[2];
    int blk = blockIdx.x;            // b*2 + which
    int b = blk >> 1, which = blk & 1;
    int t = threadIdx.x;             // 0..127

    for (int k = t; k < KK; k += 128) {
        int ia = idxA[b * KK + k];
        int nn = minN[b * KK + k];
        int rowA = ia >> 7, colA = ia & 127;
        int rowB = nn >> 7, colB = nn & 127;
        xS[k] = (which == 0) ? (float)(rowB - rowA) : (float)(colA - colB);
    }
    __syncthreads();

    const float* W1 = which ? W1c : W1r;
    const float* b1 = which ? b1c : b1r;
    const float* W2 = which ? W2c : W2r;
    const float* b2 = which ? b2c : b2r;

    float h = b1[t];
    for (int k = 0; k < KK; ++k) h = fmaf(xS[k], W1[k * HID + t], h);
    h = fmaxf(h, 0.f);
    float pv = h * W2[t];
    for (int off = 32; off > 0; off >>= 1) pv += __shfl_down(pv, off, 64);
    if ((t & 63) == 0) red[t >> 6] = pv;
    __syncthreads();
    if (t == 0) out[b * 2 + which] = red[0] + red[1] + b2[0];
}

// =====================================================================
extern "C" void kernel_launch(void* const* d_in, const int* in_sizes, int n_in,
                              void* d_out, int out_size, void* d_ws, size_t ws_size,
                              hipStream_t stream)
{
    const float* xA  = (const float*)d_in[0];
    const float* xB  = (const float*)d_in[1];
    const float* Wc  = (const float*)d_in[2];
    const float* bc  = (const float*)d_in[3];
    const float* W1r = (const float*)d_in[4];
    const float* b1r = (const float*)d_in[5];
    const float* W2r = (const float*)d_in[6];
    const float* b2r = (const float*)d_in[7];
    const float* W1c = (const float*)d_in[8];
    const float* b1c = (const float*)d_in[9];
    const float* W2c = (const float*)d_in[10];
    const float* b2c = (const float*)d_in[11];
    float* out = (float*)d_out;

    char* ws = (char*)d_ws;
    unsigned long long* scratch = (unsigned long long*)ws; ws += (size_t)NB * KK * 256 * 8;
    int*   idxA   = (int*)ws;      ws += (size_t)NB * KK * 4;
    int*   minN   = (int*)ws;      ws += (size_t)NB * KK * 4;
    float* normA  = (float*)ws;    ws += (size_t)NB * KK * 4;
    float* resp   = (float*)ws;    ws += (size_t)NB * NF * 4;
    float* normB  = (float*)ws;    ws += (size_t)NB * NF * 4;
    ushort_t* desc_h = (ushort_t*)ws; ws += (size_t)NB * KK * COUT * 2;
    ushort_t* desc_l = (ushort_t*)ws; ws += (size_t)NB * KK * COUT * 2;
    float* fB     = (float*)ws;    ws += (size_t)NB * COUT * NF * 4;

    conv_kernel  <<<512, 256, 0, stream>>>(xA, xB, Wc, bc, fB, resp, normB);
    pool_kernel  <<<NB * KK, 64, 0, stream>>>(resp, idxA);
    gather_kernel<<<NB * KK, 256, 0, stream>>>(xA, Wc, bc, idxA, desc_h, desc_l, normA);
    knn_kernel   <<<dim3(256, NB), 256, 0, stream>>>(fB, desc_h, desc_l, normA, normB, scratch);
    reduce_kernel<<<NB * KK, 64, 0, stream>>>(scratch, minN);
    mlp_kernel   <<<8, 128, 0, stream>>>(idxA, minN,
                                         W1r, b1r, W2r, b2r,
                                         W1c, b1c, W2c, b2c, out);
}